// Round 13
// baseline (273.056 us; speedup 1.0000x reference)
//
#include <hip/hip_runtime.h>
#include <cstdint>
#include <cstddef>

#define D_MODEL 256
#define D_STATE 64
#define HEADDIM 64
#define D_INNER 512
#define NHEADS 8
#define D_XBC 640
#define NPROJ 1160
#define ZXW 1152   /* bf16 zxbc row width (z + xBC) */
#define BATCH 64
#define SEQ 250
#define ROWS (BATCH * SEQ) /* 16000 */
#define KIN 240
#define KPAD 256
#define NPAD 1216
#define TPAD 256  /* t padded to 256 in xcT */

typedef __bf16 bf16x8 __attribute__((ext_vector_type(8)));
typedef float f32x4 __attribute__((ext_vector_type(4)));

__device__ __forceinline__ float readlane_f(float v, int lane) {
    return __uint_as_float(__builtin_amdgcn_readlane(__float_as_uint(v), lane));
}
__device__ __forceinline__ float silu_f(float x) { return x * (1.f / (1.f + __expf(-x))); }
__device__ __forceinline__ unsigned short bf16_rne(float f) {
    unsigned int u = __float_as_uint(f);
    u += 0x7fff + ((u >> 16) & 1);
    return (unsigned short)(u >> 16);
}
__device__ __forceinline__ float bf2f(unsigned short u) {
    return __uint_as_float(((unsigned int)u) << 16);
}
__device__ __forceinline__ unsigned int pack2(float a, float b) {
    return (unsigned int)bf16_rne(a) | ((unsigned int)bf16_rne(b) << 16);
}

// ---------------------------------------------------------------------------
// Kernel 0: cast W_in -> Bt_bf [1216][256] (transposed bf16; zero-padded)
// ---------------------------------------------------------------------------
__global__ __launch_bounds__(256) void cast_w_kernel(const float* __restrict__ Win,
                                                     unsigned short* __restrict__ bt_bf) {
    int idx = blockIdx.x * 256 + threadIdx.x;  // NPAD*KPAD total
    int n = idx >> 8, k = idx & 255;
    float v = (n < NPROJ && k < KIN) ? Win[k * NPROJ + n] : 0.f;
    bt_bf[idx] = bf16_rne(v);
}

// ---------------------------------------------------------------------------
// Kernel 1: gemm1 v6 — R10-exact structure (grid 250, X staged once, A-frags
// in regs, 19 col-tiles through one reused LDS buffer, R10 epilogue) plus ONE
// change: B-tile j+1 register-prefetched across MFMA(j) to hide load latency.
// ---------------------------------------------------------------------------
#define SB 272  /* LDS row stride in bf16 */
__global__ __launch_bounds__(256) void gemm1_mfma(const float* __restrict__ X,
                                                  const unsigned short* __restrict__ Bt,
                                                  unsigned short* __restrict__ Czx,
                                                  float* __restrict__ dtraw) {
    __shared__ unsigned short S[64 * SB];
    const int tid = threadIdx.x;
    const int lane = tid & 63, w = tid >> 6;
    const int q = lane >> 4, l15 = lane & 15;
    const int rowBase = blockIdx.x * 64;

    const int r = tid >> 2, seg = tid & 3;

    // ---- Phase 1: stage X stripe (64 x 240 fp32 -> bf16; cols 240..255 = 0)
    {
        const float* xr = X + (size_t)(rowBase + r) * KIN;
#pragma unroll
        for (int i = 0; i < 15; i++) {
            int c4 = seg * 15 + i;  // float4 index 0..59
            float4 v = *(const float4*)&xr[c4 * 4];
            unsigned short t4[4];
            t4[0] = bf16_rne(v.x); t4[1] = bf16_rne(v.y);
            t4[2] = bf16_rne(v.z); t4[3] = bf16_rne(v.w);
            *(uint2*)&S[r * SB + c4 * 4] = *(uint2*)t4;
        }
        if (seg < 2) {
            uint4 z = {0, 0, 0, 0};
            *(uint4*)&S[r * SB + 240 + seg * 8] = z;
        }
    }
    __syncthreads();
    // A-fragments: wave w owns rows w*16 .. w*16+15; all 8 k-steps in regs
    bf16x8 afr[8];
#pragma unroll
    for (int kk = 0; kk < 8; kk++)
        afr[kk] = *(const bf16x8*)&S[(w * 16 + l15) * SB + kk * 32 + q * 8];

    // ---- prefetch first B tile into registers
    uint4 breg[8];
    {
        const unsigned short* br = Bt + (size_t)r * KPAD;
#pragma unroll
        for (int i = 0; i < 8; i++)
            breg[i] = *(const uint4*)&br[seg * 8 + i * 32];
    }

    // ---- Phase 2: pipelined col-tile loop over all 19 tiles
    for (int j = 0; j < 19; j++) {
        __syncthreads();  // all prior reads of S are done (afr or MFMA of j-1)
#pragma unroll
        for (int i = 0; i < 8; i++) {
            int c = seg * 8 + i * 32;
            int cs = c ^ ((r & 3) << 3);  // XOR-swizzled dest
            *(uint4*)&S[r * SB + cs] = breg[i];
        }
        if (j + 1 < 19) {  // issue next tile's loads; they fly across MFMA
            const unsigned short* br = Bt + (size_t)((j + 1) * 64 + r) * KPAD;
#pragma unroll
            for (int i = 0; i < 8; i++)
                breg[i] = *(const uint4*)&br[seg * 8 + i * 32];
        }
        __syncthreads();  // S writes visible

        f32x4 acc[4] = {};
#pragma unroll
        for (int kk = 0; kk < 8; kk++) {
#pragma unroll
            for (int nt = 0; nt < 4; nt++) {
                int row = nt * 16 + l15;
                int c = kk * 32 + q * 8;
                int cs = c ^ ((row & 3) << 3);
                bf16x8 bfr = *(const bf16x8*)&S[row * SB + cs];
                acc[nt] = __builtin_amdgcn_mfma_f32_16x16x32_bf16(afr[kk], bfr,
                                                                  acc[nt], 0, 0, 0);
            }
        }
        // epilogue (R10-proven): row = rowBase+w*16+q*4+reg, col = j*64+nt*16+l15
        if (j < 18) {
#pragma unroll
            for (int nt = 0; nt < 4; nt++) {
                int gcol = j * 64 + nt * 16 + l15;
#pragma unroll
                for (int reg = 0; reg < 4; reg++) {
                    int grow = rowBase + w * 16 + q * 4 + reg;
                    unsigned int u = bf16_rne(acc[nt][reg]);
                    unsigned int partner = (unsigned int)__shfl_xor((int)u, 1, 64);
                    if ((l15 & 1) == 0)
                        *(unsigned int*)&Czx[(size_t)grow * ZXW + gcol] =
                            u | (partner << 16);
                }
            }
        } else {
            if (l15 < 8) {  // cols 1152..1159 = dt heads, fp32 (nt=0)
#pragma unroll
                for (int reg = 0; reg < 4; reg++) {
                    int grow = rowBase + w * 16 + q * 4 + reg;
                    dtraw[(size_t)grow * NHEADS + l15] = acc[0][reg];
                }
            }
        }
    }
}

// ---------------------------------------------------------------------------
// Kernel 2: conv v3 — tiled depthwise conv4 + SiLU from bf16 zxbc; writes
// bf16 xc_bf[b][t][640] and xcT_bf[b][640][256]. blockIdx.y==10: softplus(dt).
// ---------------------------------------------------------------------------
#define CT_IN_STR 68
#define CT_TR_STR 70
__global__ __launch_bounds__(256) void conv_kernel(const unsigned short* __restrict__ zxbc,
                                                   const float* __restrict__ dtraw,
                                                   const float* __restrict__ conv_w,
                                                   const float* __restrict__ conv_b,
                                                   const float* __restrict__ dt_bias,
                                                   unsigned short* __restrict__ xc_bf,
                                                   unsigned short* __restrict__ xcT_bf,
                                                   float* __restrict__ dtp) {
    const int b = blockIdx.x;
    const int t0 = blockIdx.z * 64;
    if (blockIdx.y == 10) {  // dt path: 64 t x 8 h
        for (int it = threadIdx.x; it < 512; it += 256) {
            int h = it & 7;
            int t = t0 + (it >> 3);
            if (t < SEQ) {
                float v = dtraw[(size_t)(b * SEQ + t) * NHEADS + h] + dt_bias[h];
                dtp[(size_t)(b * SEQ + t) * NHEADS + h] =
                    (v > 20.f) ? v : __logf(1.f + __expf(v));
            }
        }
        return;
    }
    __shared__ float In[67 * CT_IN_STR];
    __shared__ unsigned short OutT[64 * CT_TR_STR];
    const int cg = blockIdx.y;
    const int tid = threadIdx.x;
    const int lane = tid & 63;
    const int w = tid >> 6;
    const int ch = cg * 64 + lane;

    for (int r = w; r < 67; r += 4) {
        int t = t0 - 3 + r;
        float v = (t >= 0 && t < SEQ)
                      ? bf2f(zxbc[(size_t)(b * SEQ + t) * ZXW + D_INNER + ch])
                      : 0.f;
        In[r * CT_IN_STR + lane] = v;
    }
    __syncthreads();
    const float w0 = conv_w[ch * 4 + 0], w1 = conv_w[ch * 4 + 1];
    const float w2 = conv_w[ch * 4 + 2], w3 = conv_w[ch * 4 + 3];
    const float bias = conv_b[ch];
    unsigned short vals[16];
#pragma unroll
    for (int i = 0; i < 16; i++) {
        int tt = w * 16 + i;
        float acc = fmaf(w3, In[(tt + 3) * CT_IN_STR + lane],
                    fmaf(w2, In[(tt + 2) * CT_IN_STR + lane],
                    fmaf(w1, In[(tt + 1) * CT_IN_STR + lane],
                    fmaf(w0, In[tt * CT_IN_STR + lane], bias))));
        float sv = silu_f(acc);
        unsigned short bv = (t0 + tt < SEQ) ? bf16_rne(sv) : (unsigned short)0;
        vals[i] = bv;
        OutT[lane * CT_TR_STR + tt] = bv;
    }
#pragma unroll
    for (int i = 0; i < 16; i++) {
        int tt = w * 16 + i;
        if (t0 + tt < SEQ)
            xc_bf[(size_t)(b * SEQ + t0 + tt) * D_XBC + ch] = vals[i];
    }
    __syncthreads();
    unsigned short* dstbase = xcT_bf + ((size_t)b * D_XBC + cg * 64) * TPAD + t0;
#pragma unroll
    for (int i = 0; i < 16; i++) {
        int c2 = w * 16 + i;
        dstbase[(size_t)c2 * TPAD + lane] = OutT[c2 * CT_TR_STR + lane];
    }
}

// ---------------------------------------------------------------------------
// Kernel 3a: scan_intra — one block per (b,h,chunk).
// ---------------------------------------------------------------------------
#define LSTR 72
__global__ __launch_bounds__(256) void scan_intra(const unsigned short* __restrict__ xc_bf,
                                                  const unsigned short* __restrict__ xcT_bf,
                                                  const float* __restrict__ dtp,
                                                  const float* __restrict__ A_log,
                                                  const float* __restrict__ Dvec,
                                                  unsigned short* __restrict__ yout_bf,
                                                  unsigned short* __restrict__ st_g) {
    __shared__ unsigned short C_l[64 * LSTR];   // C, then (post-S3) BwT
    __shared__ unsigned short BP_l[64 * LSTR];  // B, then (post-S3) P
    __shared__ unsigned short XT_l[64 * LSTR];  // x^T (plain)
    __shared__ float cs_s[64], dts_s[64], fws_s[64];

    const int blk = blockIdx.x;
    const int bh = blk >> 2, c = blk & 3;
    const int b = bh >> 3, h = bh & 7;
    const int tid = threadIdx.x;
    const int lane = tid & 63, w = tid >> 6;
    const int q = lane >> 4, l15 = lane & 15;
    const int t0 = c * 64;
    const float A = -__expf(A_log[h]);
    const float Dh = Dvec[h];

    const int r = tid >> 2, c0 = (tid & 3) * 16;

    {
        if (t0 + r < SEQ) {
            const unsigned short* rowp = xc_bf + (size_t)(b * SEQ + t0 + r) * D_XBC;
            *(uint4*)&C_l[r * LSTR + c0] = *(const uint4*)&rowp[D_INNER + D_STATE + c0];
            *(uint4*)&C_l[r * LSTR + c0 + 8] =
                *(const uint4*)&rowp[D_INNER + D_STATE + c0 + 8];
            *(uint4*)&BP_l[r * LSTR + c0] = *(const uint4*)&rowp[D_INNER + c0];
            *(uint4*)&BP_l[r * LSTR + c0 + 8] = *(const uint4*)&rowp[D_INNER + c0 + 8];
        } else {
            uint4 z = {0, 0, 0, 0};
            *(uint4*)&C_l[r * LSTR + c0] = z;
            *(uint4*)&C_l[r * LSTR + c0 + 8] = z;
            *(uint4*)&BP_l[r * LSTR + c0] = z;
            *(uint4*)&BP_l[r * LSTR + c0 + 8] = z;
        }
        const unsigned short* xrow =
            xcT_bf + ((size_t)b * D_XBC + h * HEADDIM + r) * TPAD + t0;
        *(uint4*)&XT_l[r * LSTR + c0] = *(const uint4*)&xrow[c0];
        *(uint4*)&XT_l[r * LSTR + c0 + 8] = *(const uint4*)&xrow[c0 + 8];
    }
    uint4 braw0, braw1;
    {
        const unsigned short* brow =
            xcT_bf + ((size_t)b * D_XBC + D_INNER + r) * TPAD + t0 + c0;
        braw0 = *(const uint4*)&brow[0];
        braw1 = *(const uint4*)&brow[8];
    }
    if (w == 0) {
        int t = lane;
        float dtv = (t0 + t < SEQ) ? dtp[(size_t)(b * SEQ + t0 + t) * NHEADS + h] : 0.f;
        float csv = dtv * A;
#pragma unroll
        for (int o = 1; o < 64; o <<= 1) {
            float u = __shfl_up(csv, o, 64);
            if (lane >= o) csv += u;
        }
        float tot = readlane_f(csv, 63);
        cs_s[t] = csv;
        dts_s[t] = dtv;
        fws_s[t] = dtv * __expf(tot - csv);
    }
    __syncthreads();  // S1

    f32x4 g[4] = {};
#pragma unroll
    for (int k0 = 0; k0 < 64; k0 += 32) {
        bf16x8 ca = *(const bf16x8*)&C_l[(w * 16 + l15) * LSTR + k0 + q * 8];
#pragma unroll
        for (int nt = 0; nt < 4; nt++) {
            bf16x8 bb = *(const bf16x8*)&BP_l[(nt * 16 + l15) * LSTR + k0 + q * 8];
            g[nt] = __builtin_amdgcn_mfma_f32_16x16x32_bf16(ca, bb, g[nt], 0, 0, 0);
        }
    }
    __syncthreads();  // S3

    {
        unsigned short tmp[16];
        const unsigned short* rp = (const unsigned short*)&braw0;
#pragma unroll
        for (int j = 0; j < 8; j++) tmp[j] = bf16_rne(bf2f(rp[j]) * fws_s[c0 + j]);
        rp = (const unsigned short*)&braw1;
#pragma unroll
        for (int j = 0; j < 8; j++) tmp[8 + j] = bf16_rne(bf2f(rp[j]) * fws_s[c0 + 8 + j]);
        *(uint4*)&C_l[r * LSTR + c0] = *(uint4*)&tmp[0];
        *(uint4*)&C_l[r * LSTR + c0 + 8] = *(uint4*)&tmp[8];
    }
#pragma unroll
    for (int nt = 0; nt < 4; nt++) {
#pragma unroll
        for (int rr = 0; rr < 4; rr++) {
            int t = w * 16 + q * 4 + rr;
            int s = nt * 16 + l15;
            float pv = 0.f;
            if (s <= t) {
                pv = g[nt][rr] * __expf(cs_s[t] - cs_s[s]) * dts_s[s];
                if (s == t) pv += Dh;
            }
            unsigned int u = bf16_rne(pv);
            unsigned int partner = (unsigned int)__shfl_xor((int)u, 1, 64);
            if ((l15 & 1) == 0)
                *(unsigned int*)&BP_l[t * LSTR + nt * 16 + l15] = u | (partner << 16);
        }
    }
    __syncthreads();  // S4

    f32x4 y[4] = {};
#pragma unroll
    for (int k0 = 0; k0 < 64; k0 += 32) {
        bf16x8 pa = *(const bf16x8*)&BP_l[(w * 16 + l15) * LSTR + k0 + q * 8];
#pragma unroll
        for (int nt = 0; nt < 4; nt++) {
            bf16x8 xb = *(const bf16x8*)&XT_l[(nt * 16 + l15) * LSTR + k0 + q * 8];
            y[nt] = __builtin_amdgcn_mfma_f32_16x16x32_bf16(pa, xb, y[nt], 0, 0, 0);
        }
    }
    if (c < 3) {
        f32x4 st[4] = {};
#pragma unroll
        for (int k0 = 0; k0 < 64; k0 += 32) {
            bf16x8 xa = *(const bf16x8*)&XT_l[(w * 16 + l15) * LSTR + k0 + q * 8];
#pragma unroll
            for (int nt = 0; nt < 4; nt++) {
                bf16x8 bwb = *(const bf16x8*)&C_l[(nt * 16 + l15) * LSTR + k0 + q * 8];
                st[nt] = __builtin_amdgcn_mfma_f32_16x16x32_bf16(xa, bwb, st[nt], 0, 0, 0);
            }
        }
        unsigned short* stc = st_g + ((size_t)(bh * 3 + c)) * 4096;
#pragma unroll
        for (int nt = 0; nt < 4; nt++)
#pragma unroll
            for (int rr = 0; rr < 4; rr++) {
                unsigned int u = bf16_rne(st[nt][rr]);
                unsigned int partner = (unsigned int)__shfl_xor((int)u, 1, 64);
                if ((l15 & 1) == 0)
                    *(unsigned int*)&stc[(w * 16 + q * 4 + rr) * 64 + nt * 16 + l15] =
                        u | (partner << 16);
            }
    }
#pragma unroll
    for (int nt = 0; nt < 4; nt++)
#pragma unroll
        for (int rr = 0; rr < 4; rr++) {
            int t = w * 16 + q * 4 + rr;
            if (t0 + t < SEQ) {
                int p = nt * 16 + l15;
                unsigned int u = bf16_rne(y[nt][rr]);
                unsigned int partner = (unsigned int)__shfl_xor((int)u, 1, 64);
                if ((l15 & 1) == 0)
                    *(unsigned int*)&yout_bf[(size_t)(b * SEQ + t0 + t) * D_INNER +
                                             h * HEADDIM + p] = u | (partner << 16);
            }
        }
}

// ---------------------------------------------------------------------------
// Kernel 3b: scan_inter — one block per (b,h,c), c in {1,2,3}.
// ---------------------------------------------------------------------------
__global__ __launch_bounds__(256) void scan_inter(const unsigned short* __restrict__ xc_bf,
                                                  const float* __restrict__ dtp,
                                                  const float* __restrict__ A_log,
                                                  unsigned short* __restrict__ yout_bf,
                                                  const unsigned short* __restrict__ st_g) {
    __shared__ unsigned short C_l[64 * LSTR];
    __shared__ unsigned short h_l[64 * LSTR];
    __shared__ float cs_s[64];
    __shared__ float csum[4];

    const int blk = blockIdx.x;
    const int bh = blk / 3, c = (blk - bh * 3) + 1;
    const int b = bh >> 3, h = bh & 7;
    const int tid = threadIdx.x;
    const int lane = tid & 63, w = tid >> 6;
    const int q = lane >> 4, l15 = lane & 15;
    const int t0 = c * 64;
    const float A = -__expf(A_log[h]);

    {
        int t = lane;
        int gt = w * 64 + t;
        float dtv = (gt < SEQ) ? dtp[(size_t)(b * SEQ + gt) * NHEADS + h] : 0.f;
        float csv = dtv * A;
#pragma unroll
        for (int o = 1; o < 64; o <<= 1) {
            float u = __shfl_up(csv, o, 64);
            if (lane >= o) csv += u;
        }
        if (w == c) cs_s[t] = csv;
        if (lane == 63) csum[w] = csv;
    }
    {
        int r = tid >> 2, c0 = (tid & 3) * 16;
        if (t0 + r < SEQ) {
            const unsigned short* rowp = xc_bf + (size_t)(b * SEQ + t0 + r) * D_XBC;
            *(uint4*)&C_l[r * LSTR + c0] = *(const uint4*)&rowp[D_INNER + D_STATE + c0];
            *(uint4*)&C_l[r * LSTR + c0 + 8] =
                *(const uint4*)&rowp[D_INNER + D_STATE + c0 + 8];
        } else {
            uint4 z = {0, 0, 0, 0};
            *(uint4*)&C_l[r * LSTR + c0] = z;
            *(uint4*)&C_l[r * LSTR + c0 + 8] = z;
        }
    }
    __syncthreads();

    {
        float wgt[3];
        for (int cp = 0; cp < c; cp++) {
            float s = 0.f;
            for (int j = cp + 1; j < c; j++) s += csum[j];
            wgt[cp] = __expf(s);
        }
        const unsigned short* stb = st_g + (size_t)bh * 3 * 4096;
        for (int i = tid; i < 4096; i += 256) {
            float acc = 0.f;
            for (int cp = 0; cp < c; cp++) acc += wgt[cp] * bf2f(stb[cp * 4096 + i]);
            h_l[(i >> 6) * LSTR + (i & 63)] = bf16_rne(acc);
        }
    }
    __syncthreads();

    f32x4 in[4] = {};
#pragma unroll
    for (int k0 = 0; k0 < 64; k0 += 32) {
        bf16x8 ca = *(const bf16x8*)&C_l[(w * 16 + l15) * LSTR + k0 + q * 8];
#pragma unroll
        for (int nt = 0; nt < 4; nt++) {
            bf16x8 hb = *(const bf16x8*)&h_l[(nt * 16 + l15) * LSTR + k0 + q * 8];
            in[nt] = __builtin_amdgcn_mfma_f32_16x16x32_bf16(ca, hb, in[nt], 0, 0, 0);
        }
    }
#pragma unroll
    for (int nt = 0; nt < 4; nt++)
#pragma unroll
        for (int r = 0; r < 4; r++) {
            int t = w * 16 + q * 4 + r;
            if (t0 + t < SEQ) {
                int p = nt * 16 + l15;
                size_t ai = (size_t)(b * SEQ + t0 + t) * D_INNER + h * HEADDIM + p;
                float alpha = __expf(cs_s[t]);
                float nv = bf2f(yout_bf[ai]) + alpha * in[nt][r];
                unsigned int u = bf16_rne(nv);
                unsigned int partner = (unsigned int)__shfl_xor((int)u, 1, 64);
                if ((l15 & 1) == 0)
                    *(unsigned int*)&yout_bf[ai] = u | (partner << 16);
            }
        }
}

// ---------------------------------------------------------------------------
// Kernel 4: wcast — W_out[512][256] -> wt_bf[256][512]
// ---------------------------------------------------------------------------
__global__ __launch_bounds__(256) void wcast_kernel(const float* __restrict__ Wout,
                                                    unsigned short* __restrict__ wt_bf) {
    int idx = blockIdx.x * 256 + threadIdx.x;
    int n = idx & 255, k = idx >> 8;
    wt_bf[n * D_INNER + k] = bf16_rne(Wout[k * D_MODEL + n]);
}

// ---------------------------------------------------------------------------
// Kernel 5: gate — g = y*silu(z); row rms; g_bf = bf16(g*rms*norm_w).
// ---------------------------------------------------------------------------
__global__ __launch_bounds__(256) void gate_kernel(const unsigned short* __restrict__ yout_bf,
                                                   const unsigned short* __restrict__ zxbc,
                                                   const float* __restrict__ norm_w,
                                                   unsigned short* __restrict__ g_bf) {
    const int wid = threadIdx.x >> 6, lane = threadIdx.x & 63;
    const int row = blockIdx.x * 4 + wid;
    const unsigned short* yr = yout_bf + (size_t)row * D_INNER;
    const unsigned short* zr = zxbc + (size_t)row * ZXW;
    const int c0 = lane * 8;
    uint4 yp = *(const uint4*)&yr[c0];
    uint4 zp = *(const uint4*)&zr[c0];
    const unsigned short* ys = (const unsigned short*)&yp;
    const unsigned short* zs = (const unsigned short*)&zp;
    float g[8];
#pragma unroll
    for (int i = 0; i < 8; i++) g[i] = bf2f(ys[i]) * silu_f(bf2f(zs[i]));
    float s = 0.f;
#pragma unroll
    for (int i = 0; i < 8; i++) s = fmaf(g[i], g[i], s);
#pragma unroll
    for (int o = 32; o; o >>= 1) s += __shfl_xor(s, o, 64);
    float rms = rsqrtf(s * (1.f / 512.f) + 1e-5f);
    float4 w0 = *(const float4*)&norm_w[c0], w1 = *(const float4*)&norm_w[c0 + 4];
    uint4 pk;
    pk.x = pack2(g[0] * rms * w0.x, g[1] * rms * w0.y);
    pk.y = pack2(g[2] * rms * w0.z, g[3] * rms * w0.w);
    pk.z = pack2(g[4] * rms * w1.x, g[5] * rms * w1.y);
    pk.w = pack2(g[6] * rms * w1.z, g[7] * rms * w1.w);
    *(uint4*)&g_bf[(size_t)row * D_INNER + c0] = pk;
}

// ---------------------------------------------------------------------------
// Kernel 6: out = selu( g_bf @ wt_bf^T )[:, :240] via bf16 MFMA. K=512.
// ---------------------------------------------------------------------------
#define SA 40
__global__ __launch_bounds__(256) void gemm2_mfma(const unsigned short* __restrict__ A,
                                                  const unsigned short* __restrict__ Bt,
                                                  float* __restrict__ out) {
    __shared__ unsigned short As[128 * SA];
    __shared__ unsigned short Bs[64 * SA];
    const int tid = threadIdx.x;
    const int lane = tid & 63, wave = tid >> 6;
    const int wm = wave >> 1, wn = wave & 1;
    const int q = lane >> 4, l15 = lane & 15;
    const int rowBase = blockIdx.y * 128, colBase = blockIdx.x * 64;
    f32x4 acc[4][2] = {};

    const int sr = tid >> 2;
    const int sc = (tid & 3) * 8;

    for (int k0 = 0; k0 < D_INNER; k0 += 32) {
        *(float4*)&As[sr * SA + sc] =
            *(const float4*)&A[(size_t)(rowBase + sr) * D_INNER + k0 + sc];
        *(float4*)&As[(sr + 64) * SA + sc] =
            *(const float4*)&A[(size_t)(rowBase + sr + 64) * D_INNER + k0 + sc];
        *(float4*)&Bs[sr * SA + sc] =
            *(const float4*)&Bt[(size_t)(colBase + sr) * D_INNER + k0 + sc];
        __syncthreads();

        bf16x8 bfr[2];
#pragma unroll
        for (int nt = 0; nt < 2; nt++)
            bfr[nt] = *(const bf16x8*)&Bs[(wn * 32 + nt * 16 + l15) * SA + q * 8];
#pragma unroll
        for (int mt = 0; mt < 4; mt++) {
            bf16x8 afr = *(const bf16x8*)&As[(wm * 64 + mt * 16 + l15) * SA + q * 8];
#pragma unroll
            for (int nt = 0; nt < 2; nt++)
                acc[mt][nt] = __builtin_amdgcn_mfma_f32_16x16x32_bf16(afr, bfr[nt],
                                                                      acc[mt][nt], 0, 0, 0);
        }
        __syncthreads();
    }
    const float SC = 1.0507009873554805f, AL = 1.6732632423543772f;
#pragma unroll
    for (int mt = 0; mt < 4; mt++) {
        int grow = rowBase + wm * 64 + mt * 16 + q * 4;
#pragma unroll
        for (int nt = 0; nt < 2; nt++) {
            int gcol = colBase + wn * 32 + nt * 16 + l15;
            if (gcol < 240) {
#pragma unroll
                for (int reg = 0; reg < 4; reg++) {
                    float v = acc[mt][nt][reg];
                    v = (v > 0.f) ? SC * v : SC * AL * (__expf(v) - 1.f);
                    out[(size_t)(grow + reg) * 240 + gcol] = v;
                }
            }
        }
    }
}

// ---------------------------------------------------------------------------
extern "C" void kernel_launch(void* const* d_in, const int* in_sizes, int n_in,
                              void* d_out, int out_size, void* d_ws, size_t ws_size,
                              hipStream_t stream) {
    const float* x = (const float*)d_in[0];
    const float* W_in = (const float*)d_in[1];
    const float* conv_w = (const float*)d_in[2];
    const float* conv_b = (const float*)d_in[3];
    const float* A_log = (const float*)d_in[4];
    const float* dt_bias = (const float*)d_in[5];
    const float* Dv = (const float*)d_in[6];
    const float* norm_w = (const float*)d_in[7];
    const float* W_out = (const float*)d_in[8];
    float* out = (float*)d_out;

    unsigned short* us = (unsigned short*)d_ws;
    unsigned short* zxbc_bf = us;                              // 16000*1152
    unsigned short* xc_bf = zxbc_bf + (size_t)ROWS * ZXW;      // 16000*640
    unsigned short* xcT_bf = xc_bf + (size_t)ROWS * D_XBC;     // 64*640*256
    unsigned short* yout_bf = xcT_bf + (size_t)BATCH * D_XBC * TPAD;  // 16000*512
    unsigned short* st_g = yout_bf + (size_t)ROWS * D_INNER;   // 512*3*4096
    unsigned short* bt_bf = st_g + (size_t)512 * 3 * 4096;     // 1216*256
    unsigned short* wt_bf = bt_bf + (size_t)NPAD * KPAD;       // 256*512
    unsigned short* g_bf = wt_bf + (size_t)D_MODEL * D_INNER;  // 16000*512
    float* dtraw = (float*)(g_bf + (size_t)ROWS * D_INNER);    // 16000*8
    float* dtp = dtraw + (size_t)ROWS * NHEADS;                // 16000*8

    cast_w_kernel<<<dim3(NPAD * KPAD / 256), 256, 0, stream>>>(W_in, bt_bf);

    gemm1_mfma<<<dim3(ROWS / 64), 256, 0, stream>>>(x, bt_bf, zxbc_bf, dtraw);

    conv_kernel<<<dim3(BATCH, 11, 4), 256, 0, stream>>>(zxbc_bf, dtraw, conv_w, conv_b,
                                                        dt_bias, xc_bf, xcT_bf, dtp);

    scan_intra<<<dim3(BATCH * NHEADS * 4), 256, 0, stream>>>(xc_bf, xcT_bf, dtp, A_log, Dv,
                                                             yout_bf, st_g);

    scan_inter<<<dim3(BATCH * NHEADS * 3), 256, 0, stream>>>(xc_bf, dtp, A_log,
                                                             yout_bf, st_g);

    wcast_kernel<<<dim3(D_INNER * D_MODEL / 256), 256, 0, stream>>>(W_out, wt_bf);

    gate_kernel<<<dim3(ROWS / 4), 256, 0, stream>>>(yout_bf, zxbc_bf, norm_w, g_bf);

    gemm2_mfma<<<dim3(D_MODEL / 64, ROWS / 128), 256, 0, stream>>>(g_bf, wt_bf, out);
}

// Round 14
// 212.223 us; speedup vs baseline: 1.2866x; 1.2866x over previous
//
#include <hip/hip_runtime.h>
#include <cstdint>
#include <cstddef>

#define D_MODEL 256
#define D_STATE 64
#define HEADDIM 64
#define D_INNER 512
#define NHEADS 8
#define D_XBC 640
#define NPROJ 1160
#define ZXW 1152   /* bf16 zxbc row width (z + xBC) */
#define BATCH 64
#define SEQ 250
#define ROWS (BATCH * SEQ) /* 16000 */
#define KIN 240
#define KPAD 256
#define NPAD 1216
#define TPAD 256  /* t padded to 256 in xcT */

typedef __bf16 bf16x8 __attribute__((ext_vector_type(8)));
typedef float f32x4 __attribute__((ext_vector_type(4)));

__device__ __forceinline__ float readlane_f(float v, int lane) {
    return __uint_as_float(__builtin_amdgcn_readlane(__float_as_uint(v), lane));
}
__device__ __forceinline__ float silu_f(float x) { return x * (1.f / (1.f + __expf(-x))); }
__device__ __forceinline__ unsigned short bf16_rne(float f) {
    unsigned int u = __float_as_uint(f);
    u += 0x7fff + ((u >> 16) & 1);
    return (unsigned short)(u >> 16);
}
__device__ __forceinline__ float bf2f(unsigned short u) {
    return __uint_as_float(((unsigned int)u) << 16);
}
__device__ __forceinline__ unsigned int pack2(float a, float b) {
    return (unsigned int)bf16_rne(a) | ((unsigned int)bf16_rne(b) << 16);
}

// ---------------------------------------------------------------------------
// Kernel 0: cast_all — x -> a_bf [16000][256], W_in -> bt_bf [1216][256] (T),
// W_out -> wt_bf [256][512] (T). One launch for all three.
// ---------------------------------------------------------------------------
#define NA (ROWS * KPAD)
#define NB (NPAD * KPAD)
#define NW (D_MODEL * D_INNER)
__global__ __launch_bounds__(256) void cast_all_kernel(const float* __restrict__ x,
                                                       const float* __restrict__ Win,
                                                       const float* __restrict__ Wout,
                                                       unsigned short* __restrict__ a_bf,
                                                       unsigned short* __restrict__ bt_bf,
                                                       unsigned short* __restrict__ wt_bf) {
    int idx = blockIdx.x * 256 + threadIdx.x;
    if (idx < NA) {
        int row = idx >> 8, c = idx & 255;
        float v = (c < KIN) ? x[row * KIN + c] : 0.f;
        a_bf[idx] = bf16_rne(v);
    } else if (idx < NA + NB) {
        int r = idx - NA;
        int n = r >> 8, k = r & 255;
        float v = (n < NPROJ && k < KIN) ? Win[k * NPROJ + n] : 0.f;
        bt_bf[r] = bf16_rne(v);
    } else if (idx < NA + NB + NW) {
        int r = idx - NA - NB;
        int n = r & 255, k = r >> 8;
        wt_bf[n * D_INNER + k] = bf16_rne(Wout[k * D_MODEL + n]);
    }
}

// ---------------------------------------------------------------------------
// Kernel 1: gemm1 — R9-proven structure (grid 19x125, 128x64 tile, two-stage
// LDS staging) reading PRE-CAST bf16 a_bf. Writes bf16 zxbc (cols 0..1152)
// + fp32 dtraw (cols 1152..1159).
// ---------------------------------------------------------------------------
#define SA 40
__global__ __launch_bounds__(256) void gemm1_mfma(const unsigned short* __restrict__ A,
                                                  const unsigned short* __restrict__ Bt,
                                                  unsigned short* __restrict__ Czx,
                                                  float* __restrict__ dtraw) {
    __shared__ unsigned short As[128 * SA];
    __shared__ unsigned short Bs[64 * SA];
    const int tid = threadIdx.x;
    const int lane = tid & 63, wave = tid >> 6;
    const int wm = wave >> 1, wn = wave & 1;
    const int q = lane >> 4, l15 = lane & 15;
    const int rowBase = blockIdx.y * 128, colBase = blockIdx.x * 64;
    f32x4 acc[4][2] = {};

    const int sr = tid >> 2;
    const int sc = (tid & 3) * 8;

    for (int k0 = 0; k0 < KPAD; k0 += 32) {
        *(uint4*)&As[sr * SA + sc] =
            *(const uint4*)&A[(size_t)(rowBase + sr) * KPAD + k0 + sc];
        *(uint4*)&As[(sr + 64) * SA + sc] =
            *(const uint4*)&A[(size_t)(rowBase + sr + 64) * KPAD + k0 + sc];
        *(uint4*)&Bs[sr * SA + sc] =
            *(const uint4*)&Bt[(size_t)(colBase + sr) * KPAD + k0 + sc];
        __syncthreads();

        bf16x8 bfr[2];
#pragma unroll
        for (int nt = 0; nt < 2; nt++)
            bfr[nt] = *(const bf16x8*)&Bs[(wn * 32 + nt * 16 + l15) * SA + q * 8];
#pragma unroll
        for (int mt = 0; mt < 4; mt++) {
            bf16x8 afr = *(const bf16x8*)&As[(wm * 64 + mt * 16 + l15) * SA + q * 8];
#pragma unroll
            for (int nt = 0; nt < 2; nt++)
                acc[mt][nt] = __builtin_amdgcn_mfma_f32_16x16x32_bf16(afr, bfr[nt],
                                                                      acc[mt][nt], 0, 0, 0);
        }
        __syncthreads();
    }
#pragma unroll
    for (int mt = 0; mt < 4; mt++) {
        int grow0 = rowBase + wm * 64 + mt * 16 + q * 4;
#pragma unroll
        for (int nt = 0; nt < 2; nt++) {
            int gcol = colBase + wn * 32 + nt * 16 + l15;
            if (gcol < ZXW) {
#pragma unroll
                for (int reg = 0; reg < 4; reg++) {
                    unsigned int u = bf16_rne(acc[mt][nt][reg]);
                    unsigned int partner = (unsigned int)__shfl_xor((int)u, 1, 64);
                    if ((l15 & 1) == 0)
                        *(unsigned int*)&Czx[(size_t)(grow0 + reg) * ZXW + gcol] =
                            u | (partner << 16);
                }
            } else if (gcol < NPROJ) {
#pragma unroll
                for (int reg = 0; reg < 4; reg++)
                    dtraw[(size_t)(grow0 + reg) * NHEADS + (gcol - ZXW)] = acc[mt][nt][reg];
            }
        }
    }
}

// ---------------------------------------------------------------------------
// Kernel 2: conv v3 — tiled depthwise conv4 + SiLU from bf16 zxbc; writes
// bf16 xc_bf[b][t][640] and xcT_bf[b][640][256]. blockIdx.y==10: softplus(dt).
// ---------------------------------------------------------------------------
#define CT_IN_STR 68
#define CT_TR_STR 70
__global__ __launch_bounds__(256) void conv_kernel(const unsigned short* __restrict__ zxbc,
                                                   const float* __restrict__ dtraw,
                                                   const float* __restrict__ conv_w,
                                                   const float* __restrict__ conv_b,
                                                   const float* __restrict__ dt_bias,
                                                   unsigned short* __restrict__ xc_bf,
                                                   unsigned short* __restrict__ xcT_bf,
                                                   float* __restrict__ dtp) {
    const int b = blockIdx.x;
    const int t0 = blockIdx.z * 64;
    if (blockIdx.y == 10) {  // dt path: 64 t x 8 h
        for (int it = threadIdx.x; it < 512; it += 256) {
            int h = it & 7;
            int t = t0 + (it >> 3);
            if (t < SEQ) {
                float v = dtraw[(size_t)(b * SEQ + t) * NHEADS + h] + dt_bias[h];
                dtp[(size_t)(b * SEQ + t) * NHEADS + h] =
                    (v > 20.f) ? v : __logf(1.f + __expf(v));
            }
        }
        return;
    }
    __shared__ float In[67 * CT_IN_STR];
    __shared__ unsigned short OutT[64 * CT_TR_STR];
    const int cg = blockIdx.y;
    const int tid = threadIdx.x;
    const int lane = tid & 63;
    const int w = tid >> 6;
    const int ch = cg * 64 + lane;

    for (int r = w; r < 67; r += 4) {
        int t = t0 - 3 + r;
        float v = (t >= 0 && t < SEQ)
                      ? bf2f(zxbc[(size_t)(b * SEQ + t) * ZXW + D_INNER + ch])
                      : 0.f;
        In[r * CT_IN_STR + lane] = v;
    }
    __syncthreads();
    const float w0 = conv_w[ch * 4 + 0], w1 = conv_w[ch * 4 + 1];
    const float w2 = conv_w[ch * 4 + 2], w3 = conv_w[ch * 4 + 3];
    const float bias = conv_b[ch];
    unsigned short vals[16];
#pragma unroll
    for (int i = 0; i < 16; i++) {
        int tt = w * 16 + i;
        float acc = fmaf(w3, In[(tt + 3) * CT_IN_STR + lane],
                    fmaf(w2, In[(tt + 2) * CT_IN_STR + lane],
                    fmaf(w1, In[(tt + 1) * CT_IN_STR + lane],
                    fmaf(w0, In[tt * CT_IN_STR + lane], bias))));
        float sv = silu_f(acc);
        unsigned short bv = (t0 + tt < SEQ) ? bf16_rne(sv) : (unsigned short)0;
        vals[i] = bv;
        OutT[lane * CT_TR_STR + tt] = bv;
    }
#pragma unroll
    for (int i = 0; i < 16; i++) {
        int tt = w * 16 + i;
        if (t0 + tt < SEQ)
            xc_bf[(size_t)(b * SEQ + t0 + tt) * D_XBC + ch] = vals[i];
    }
    __syncthreads();
    unsigned short* dstbase = xcT_bf + ((size_t)b * D_XBC + cg * 64) * TPAD + t0;
#pragma unroll
    for (int i = 0; i < 16; i++) {
        int c2 = w * 16 + i;
        dstbase[(size_t)c2 * TPAD + lane] = OutT[c2 * CT_TR_STR + lane];
    }
}

// ---------------------------------------------------------------------------
// Kernel 3a: scan_intra — one block per (b,h,chunk).
// ---------------------------------------------------------------------------
#define LSTR 72
__global__ __launch_bounds__(256) void scan_intra(const unsigned short* __restrict__ xc_bf,
                                                  const unsigned short* __restrict__ xcT_bf,
                                                  const float* __restrict__ dtp,
                                                  const float* __restrict__ A_log,
                                                  const float* __restrict__ Dvec,
                                                  unsigned short* __restrict__ yout_bf,
                                                  unsigned short* __restrict__ st_g) {
    __shared__ unsigned short C_l[64 * LSTR];   // C, then (post-S3) BwT
    __shared__ unsigned short BP_l[64 * LSTR];  // B, then (post-S3) P
    __shared__ unsigned short XT_l[64 * LSTR];  // x^T (plain)
    __shared__ float cs_s[64], dts_s[64], fws_s[64];

    const int blk = blockIdx.x;
    const int bh = blk >> 2, c = blk & 3;
    const int b = bh >> 3, h = bh & 7;
    const int tid = threadIdx.x;
    const int lane = tid & 63, w = tid >> 6;
    const int q = lane >> 4, l15 = lane & 15;
    const int t0 = c * 64;
    const float A = -__expf(A_log[h]);
    const float Dh = Dvec[h];

    const int r = tid >> 2, c0 = (tid & 3) * 16;

    {
        if (t0 + r < SEQ) {
            const unsigned short* rowp = xc_bf + (size_t)(b * SEQ + t0 + r) * D_XBC;
            *(uint4*)&C_l[r * LSTR + c0] = *(const uint4*)&rowp[D_INNER + D_STATE + c0];
            *(uint4*)&C_l[r * LSTR + c0 + 8] =
                *(const uint4*)&rowp[D_INNER + D_STATE + c0 + 8];
            *(uint4*)&BP_l[r * LSTR + c0] = *(const uint4*)&rowp[D_INNER + c0];
            *(uint4*)&BP_l[r * LSTR + c0 + 8] = *(const uint4*)&rowp[D_INNER + c0 + 8];
        } else {
            uint4 z = {0, 0, 0, 0};
            *(uint4*)&C_l[r * LSTR + c0] = z;
            *(uint4*)&C_l[r * LSTR + c0 + 8] = z;
            *(uint4*)&BP_l[r * LSTR + c0] = z;
            *(uint4*)&BP_l[r * LSTR + c0 + 8] = z;
        }
        const unsigned short* xrow =
            xcT_bf + ((size_t)b * D_XBC + h * HEADDIM + r) * TPAD + t0;
        *(uint4*)&XT_l[r * LSTR + c0] = *(const uint4*)&xrow[c0];
        *(uint4*)&XT_l[r * LSTR + c0 + 8] = *(const uint4*)&xrow[c0 + 8];
    }
    uint4 braw0, braw1;
    {
        const unsigned short* brow =
            xcT_bf + ((size_t)b * D_XBC + D_INNER + r) * TPAD + t0 + c0;
        braw0 = *(const uint4*)&brow[0];
        braw1 = *(const uint4*)&brow[8];
    }
    if (w == 0) {
        int t = lane;
        float dtv = (t0 + t < SEQ) ? dtp[(size_t)(b * SEQ + t0 + t) * NHEADS + h] : 0.f;
        float csv = dtv * A;
#pragma unroll
        for (int o = 1; o < 64; o <<= 1) {
            float u = __shfl_up(csv, o, 64);
            if (lane >= o) csv += u;
        }
        float tot = readlane_f(csv, 63);
        cs_s[t] = csv;
        dts_s[t] = dtv;
        fws_s[t] = dtv * __expf(tot - csv);
    }
    __syncthreads();  // S1

    f32x4 g[4] = {};
#pragma unroll
    for (int k0 = 0; k0 < 64; k0 += 32) {
        bf16x8 ca = *(const bf16x8*)&C_l[(w * 16 + l15) * LSTR + k0 + q * 8];
#pragma unroll
        for (int nt = 0; nt < 4; nt++) {
            bf16x8 bb = *(const bf16x8*)&BP_l[(nt * 16 + l15) * LSTR + k0 + q * 8];
            g[nt] = __builtin_amdgcn_mfma_f32_16x16x32_bf16(ca, bb, g[nt], 0, 0, 0);
        }
    }
    __syncthreads();  // S3

    {
        unsigned short tmp[16];
        const unsigned short* rp = (const unsigned short*)&braw0;
#pragma unroll
        for (int j = 0; j < 8; j++) tmp[j] = bf16_rne(bf2f(rp[j]) * fws_s[c0 + j]);
        rp = (const unsigned short*)&braw1;
#pragma unroll
        for (int j = 0; j < 8; j++) tmp[8 + j] = bf16_rne(bf2f(rp[j]) * fws_s[c0 + 8 + j]);
        *(uint4*)&C_l[r * LSTR + c0] = *(uint4*)&tmp[0];
        *(uint4*)&C_l[r * LSTR + c0 + 8] = *(uint4*)&tmp[8];
    }
#pragma unroll
    for (int nt = 0; nt < 4; nt++) {
#pragma unroll
        for (int rr = 0; rr < 4; rr++) {
            int t = w * 16 + q * 4 + rr;
            int s = nt * 16 + l15;
            float pv = 0.f;
            if (s <= t) {
                pv = g[nt][rr] * __expf(cs_s[t] - cs_s[s]) * dts_s[s];
                if (s == t) pv += Dh;
            }
            unsigned int u = bf16_rne(pv);
            unsigned int partner = (unsigned int)__shfl_xor((int)u, 1, 64);
            if ((l15 & 1) == 0)
                *(unsigned int*)&BP_l[t * LSTR + nt * 16 + l15] = u | (partner << 16);
        }
    }
    __syncthreads();  // S4

    f32x4 y[4] = {};
#pragma unroll
    for (int k0 = 0; k0 < 64; k0 += 32) {
        bf16x8 pa = *(const bf16x8*)&BP_l[(w * 16 + l15) * LSTR + k0 + q * 8];
#pragma unroll
        for (int nt = 0; nt < 4; nt++) {
            bf16x8 xb = *(const bf16x8*)&XT_l[(nt * 16 + l15) * LSTR + k0 + q * 8];
            y[nt] = __builtin_amdgcn_mfma_f32_16x16x32_bf16(pa, xb, y[nt], 0, 0, 0);
        }
    }
    if (c < 3) {
        f32x4 st[4] = {};
#pragma unroll
        for (int k0 = 0; k0 < 64; k0 += 32) {
            bf16x8 xa = *(const bf16x8*)&XT_l[(w * 16 + l15) * LSTR + k0 + q * 8];
#pragma unroll
            for (int nt = 0; nt < 4; nt++) {
                bf16x8 bwb = *(const bf16x8*)&C_l[(nt * 16 + l15) * LSTR + k0 + q * 8];
                st[nt] = __builtin_amdgcn_mfma_f32_16x16x32_bf16(xa, bwb, st[nt], 0, 0, 0);
            }
        }
        unsigned short* stc = st_g + ((size_t)(bh * 3 + c)) * 4096;
#pragma unroll
        for (int nt = 0; nt < 4; nt++)
#pragma unroll
            for (int rr = 0; rr < 4; rr++) {
                unsigned int u = bf16_rne(st[nt][rr]);
                unsigned int partner = (unsigned int)__shfl_xor((int)u, 1, 64);
                if ((l15 & 1) == 0)
                    *(unsigned int*)&stc[(w * 16 + q * 4 + rr) * 64 + nt * 16 + l15] =
                        u | (partner << 16);
            }
    }
#pragma unroll
    for (int nt = 0; nt < 4; nt++)
#pragma unroll
        for (int rr = 0; rr < 4; rr++) {
            int t = w * 16 + q * 4 + rr;
            if (t0 + t < SEQ) {
                int p = nt * 16 + l15;
                unsigned int u = bf16_rne(y[nt][rr]);
                unsigned int partner = (unsigned int)__shfl_xor((int)u, 1, 64);
                if ((l15 & 1) == 0)
                    *(unsigned int*)&yout_bf[(size_t)(b * SEQ + t0 + t) * D_INNER +
                                             h * HEADDIM + p] = u | (partner << 16);
            }
        }
}

// ---------------------------------------------------------------------------
// Kernel 3b: scan_inter — one block per (b,h,c), c in {1,2,3}.
// ---------------------------------------------------------------------------
__global__ __launch_bounds__(256) void scan_inter(const unsigned short* __restrict__ xc_bf,
                                                  const float* __restrict__ dtp,
                                                  const float* __restrict__ A_log,
                                                  unsigned short* __restrict__ yout_bf,
                                                  const unsigned short* __restrict__ st_g) {
    __shared__ unsigned short C_l[64 * LSTR];
    __shared__ unsigned short h_l[64 * LSTR];
    __shared__ float cs_s[64];
    __shared__ float csum[4];

    const int blk = blockIdx.x;
    const int bh = blk / 3, c = (blk - bh * 3) + 1;
    const int b = bh >> 3, h = bh & 7;
    const int tid = threadIdx.x;
    const int lane = tid & 63, w = tid >> 6;
    const int q = lane >> 4, l15 = lane & 15;
    const int t0 = c * 64;
    const float A = -__expf(A_log[h]);

    {
        int t = lane;
        int gt = w * 64 + t;
        float dtv = (gt < SEQ) ? dtp[(size_t)(b * SEQ + gt) * NHEADS + h] : 0.f;
        float csv = dtv * A;
#pragma unroll
        for (int o = 1; o < 64; o <<= 1) {
            float u = __shfl_up(csv, o, 64);
            if (lane >= o) csv += u;
        }
        if (w == c) cs_s[t] = csv;
        if (lane == 63) csum[w] = csv;
    }
    {
        int r = tid >> 2, c0 = (tid & 3) * 16;
        if (t0 + r < SEQ) {
            const unsigned short* rowp = xc_bf + (size_t)(b * SEQ + t0 + r) * D_XBC;
            *(uint4*)&C_l[r * LSTR + c0] = *(const uint4*)&rowp[D_INNER + D_STATE + c0];
            *(uint4*)&C_l[r * LSTR + c0 + 8] =
                *(const uint4*)&rowp[D_INNER + D_STATE + c0 + 8];
        } else {
            uint4 z = {0, 0, 0, 0};
            *(uint4*)&C_l[r * LSTR + c0] = z;
            *(uint4*)&C_l[r * LSTR + c0 + 8] = z;
        }
    }
    __syncthreads();

    {
        float wgt[3];
        for (int cp = 0; cp < c; cp++) {
            float s = 0.f;
            for (int j = cp + 1; j < c; j++) s += csum[j];
            wgt[cp] = __expf(s);
        }
        const unsigned short* stb = st_g + (size_t)bh * 3 * 4096;
        for (int i = tid; i < 4096; i += 256) {
            float acc = 0.f;
            for (int cp = 0; cp < c; cp++) acc += wgt[cp] * bf2f(stb[cp * 4096 + i]);
            h_l[(i >> 6) * LSTR + (i & 63)] = bf16_rne(acc);
        }
    }
    __syncthreads();

    f32x4 in[4] = {};
#pragma unroll
    for (int k0 = 0; k0 < 64; k0 += 32) {
        bf16x8 ca = *(const bf16x8*)&C_l[(w * 16 + l15) * LSTR + k0 + q * 8];
#pragma unroll
        for (int nt = 0; nt < 4; nt++) {
            bf16x8 hb = *(const bf16x8*)&h_l[(nt * 16 + l15) * LSTR + k0 + q * 8];
            in[nt] = __builtin_amdgcn_mfma_f32_16x16x32_bf16(ca, hb, in[nt], 0, 0, 0);
        }
    }
#pragma unroll
    for (int nt = 0; nt < 4; nt++)
#pragma unroll
        for (int r = 0; r < 4; r++) {
            int t = w * 16 + q * 4 + r;
            if (t0 + t < SEQ) {
                int p = nt * 16 + l15;
                size_t ai = (size_t)(b * SEQ + t0 + t) * D_INNER + h * HEADDIM + p;
                float alpha = __expf(cs_s[t]);
                float nv = bf2f(yout_bf[ai]) + alpha * in[nt][r];
                unsigned int u = bf16_rne(nv);
                unsigned int partner = (unsigned int)__shfl_xor((int)u, 1, 64);
                if ((l15 & 1) == 0)
                    *(unsigned int*)&yout_bf[ai] = u | (partner << 16);
            }
        }
}

// ---------------------------------------------------------------------------
// Kernel 5: gate — g = y*silu(z); row rms; g_bf = bf16(g*rms*norm_w).
// ---------------------------------------------------------------------------
__global__ __launch_bounds__(256) void gate_kernel(const unsigned short* __restrict__ yout_bf,
                                                   const unsigned short* __restrict__ zxbc,
                                                   const float* __restrict__ norm_w,
                                                   unsigned short* __restrict__ g_bf) {
    const int wid = threadIdx.x >> 6, lane = threadIdx.x & 63;
    const int row = blockIdx.x * 4 + wid;
    const unsigned short* yr = yout_bf + (size_t)row * D_INNER;
    const unsigned short* zr = zxbc + (size_t)row * ZXW;
    const int c0 = lane * 8;
    uint4 yp = *(const uint4*)&yr[c0];
    uint4 zp = *(const uint4*)&zr[c0];
    const unsigned short* ys = (const unsigned short*)&yp;
    const unsigned short* zs = (const unsigned short*)&zp;
    float g[8];
#pragma unroll
    for (int i = 0; i < 8; i++) g[i] = bf2f(ys[i]) * silu_f(bf2f(zs[i]));
    float s = 0.f;
#pragma unroll
    for (int i = 0; i < 8; i++) s = fmaf(g[i], g[i], s);
#pragma unroll
    for (int o = 32; o; o >>= 1) s += __shfl_xor(s, o, 64);
    float rms = rsqrtf(s * (1.f / 512.f) + 1e-5f);
    float4 w0 = *(const float4*)&norm_w[c0], w1 = *(const float4*)&norm_w[c0 + 4];
    uint4 pk;
    pk.x = pack2(g[0] * rms * w0.x, g[1] * rms * w0.y);
    pk.y = pack2(g[2] * rms * w0.z, g[3] * rms * w0.w);
    pk.z = pack2(g[4] * rms * w1.x, g[5] * rms * w1.y);
    pk.w = pack2(g[6] * rms * w1.z, g[7] * rms * w1.w);
    *(uint4*)&g_bf[(size_t)row * D_INNER + c0] = pk;
}

// ---------------------------------------------------------------------------
// Kernel 6: out = selu( g_bf @ wt_bf^T )[:, :240] via bf16 MFMA. K=512.
// ---------------------------------------------------------------------------
__global__ __launch_bounds__(256) void gemm2_mfma(const unsigned short* __restrict__ A,
                                                  const unsigned short* __restrict__ Bt,
                                                  float* __restrict__ out) {
    __shared__ unsigned short As[128 * SA];
    __shared__ unsigned short Bs[64 * SA];
    const int tid = threadIdx.x;
    const int lane = tid & 63, wave = tid >> 6;
    const int wm = wave >> 1, wn = wave & 1;
    const int q = lane >> 4, l15 = lane & 15;
    const int rowBase = blockIdx.y * 128, colBase = blockIdx.x * 64;
    f32x4 acc[4][2] = {};

    const int sr = tid >> 2;
    const int sc = (tid & 3) * 8;

    for (int k0 = 0; k0 < D_INNER; k0 += 32) {
        *(float4*)&As[sr * SA + sc] =
            *(const float4*)&A[(size_t)(rowBase + sr) * D_INNER + k0 + sc];
        *(float4*)&As[(sr + 64) * SA + sc] =
            *(const float4*)&A[(size_t)(rowBase + sr + 64) * D_INNER + k0 + sc];
        *(float4*)&Bs[sr * SA + sc] =
            *(const float4*)&Bt[(size_t)(colBase + sr) * D_INNER + k0 + sc];
        __syncthreads();

        bf16x8 bfr[2];
#pragma unroll
        for (int nt = 0; nt < 2; nt++)
            bfr[nt] = *(const bf16x8*)&Bs[(wn * 32 + nt * 16 + l15) * SA + q * 8];
#pragma unroll
        for (int mt = 0; mt < 4; mt++) {
            bf16x8 afr = *(const bf16x8*)&As[(wm * 64 + mt * 16 + l15) * SA + q * 8];
#pragma unroll
            for (int nt = 0; nt < 2; nt++)
                acc[mt][nt] = __builtin_amdgcn_mfma_f32_16x16x32_bf16(afr, bfr[nt],
                                                                      acc[mt][nt], 0, 0, 0);
        }
        __syncthreads();
    }
    const float SC = 1.0507009873554805f, AL = 1.6732632423543772f;
#pragma unroll
    for (int mt = 0; mt < 4; mt++) {
        int grow = rowBase + wm * 64 + mt * 16 + q * 4;
#pragma unroll
        for (int nt = 0; nt < 2; nt++) {
            int gcol = colBase + wn * 32 + nt * 16 + l15;
            if (gcol < 240) {
#pragma unroll
                for (int reg = 0; reg < 4; reg++) {
                    float v = acc[mt][nt][reg];
                    v = (v > 0.f) ? SC * v : SC * AL * (__expf(v) - 1.f);
                    out[(size_t)(grow + reg) * 240 + gcol] = v;
                }
            }
        }
    }
}

// ---------------------------------------------------------------------------
extern "C" void kernel_launch(void* const* d_in, const int* in_sizes, int n_in,
                              void* d_out, int out_size, void* d_ws, size_t ws_size,
                              hipStream_t stream) {
    const float* x = (const float*)d_in[0];
    const float* W_in = (const float*)d_in[1];
    const float* conv_w = (const float*)d_in[2];
    const float* conv_b = (const float*)d_in[3];
    const float* A_log = (const float*)d_in[4];
    const float* dt_bias = (const float*)d_in[5];
    const float* Dv = (const float*)d_in[6];
    const float* norm_w = (const float*)d_in[7];
    const float* W_out = (const float*)d_in[8];
    float* out = (float*)d_out;

    unsigned short* us = (unsigned short*)d_ws;
    unsigned short* zxbc_bf = us;                              // 16000*1152
    unsigned short* xc_bf = zxbc_bf + (size_t)ROWS * ZXW;      // 16000*640
    unsigned short* xcT_bf = xc_bf + (size_t)ROWS * D_XBC;     // 64*640*256
    unsigned short* yout_bf = xcT_bf + (size_t)BATCH * D_XBC * TPAD;  // 16000*512
    unsigned short* st_g = yout_bf + (size_t)ROWS * D_INNER;   // 512*3*4096
    unsigned short* bt_bf = st_g + (size_t)512 * 3 * 4096;     // 1216*256
    unsigned short* wt_bf = bt_bf + (size_t)NPAD * KPAD;       // 256*512
    unsigned short* g_bf = wt_bf + (size_t)D_MODEL * D_INNER;  // 16000*512
    float* dtraw = (float*)(g_bf + (size_t)ROWS * D_INNER);    // 16000*8
    float* dtp = dtraw + (size_t)ROWS * NHEADS;                // 16000*8
    unsigned short* a_bf = (unsigned short*)(dtp + (size_t)ROWS * NHEADS);  // 16000*256

    int cast_total = NA + NB + NW;
    cast_all_kernel<<<dim3((cast_total + 255) / 256), 256, 0, stream>>>(x, W_in, W_out,
                                                                        a_bf, bt_bf, wt_bf);

    gemm1_mfma<<<dim3(NPAD / 64, ROWS / 128), 256, 0, stream>>>(a_bf, bt_bf, zxbc_bf, dtraw);

    conv_kernel<<<dim3(BATCH, 11, 4), 256, 0, stream>>>(zxbc_bf, dtraw, conv_w, conv_b,
                                                        dt_bias, xc_bf, xcT_bf, dtp);

    scan_intra<<<dim3(BATCH * NHEADS * 4), 256, 0, stream>>>(xc_bf, xcT_bf, dtp, A_log, Dv,
                                                             yout_bf, st_g);

    scan_inter<<<dim3(BATCH * NHEADS * 3), 256, 0, stream>>>(xc_bf, dtp, A_log,
                                                             yout_bf, st_g);

    gate_kernel<<<dim3(ROWS / 4), 256, 0, stream>>>(yout_bf, zxbc_bf, norm_w, g_bf);

    gemm2_mfma<<<dim3(D_MODEL / 64, ROWS / 128), 256, 0, stream>>>(g_bf, wt_bf, out);
}